// Round 12
// baseline (426.882 us; speedup 1.0000x reference)
//
#include <hip/hip_runtime.h>

#define BB 32
#define HH 384
#define WW 1280
#define KS 9
#define NT 256                       // 4 waves per block
#define NPAIR 192                    // row-pairs per column
#define BSTR ((size_t)WW * NPAIR)    // f2v per batch

typedef float f2v __attribute__((ext_vector_type(2)));
typedef float4 f4;

static __device__ __forceinline__ f2v pk_mul(f2v a, f2v b) {
    f2v d; asm("v_pk_mul_f32 %0, %1, %2" : "=v"(d) : "v"(a), "v"(b)); return d;
}
static __device__ __forceinline__ f2v pk_fma(f2v a, f2v b, f2v c) {
    f2v d; asm("v_pk_fma_f32 %0, %1, %2, %3" : "=v"(d) : "v"(a), "v"(b), "v"(c)); return d;
}
// DPP wave shifts; bound_ctrl=true zero-fills edge lanes (verified rounds 2-9)
static __device__ __forceinline__ float du(float v) {   // lane i <- i-1; lane0 <- 0
    return __int_as_float(__builtin_amdgcn_mov_dpp(__float_as_int(v), 0x138, 0xf, 0xf, true));
}
static __device__ __forceinline__ float dd(float v) {   // lane i <- i+1; lane63 <- 0
    return __int_as_float(__builtin_amdgcn_mov_dpp(__float_as_int(v), 0x130, 0xf, 0xf, true));
}
template<int U> __device__ __forceinline__ void setc(f4& q, float v) {
    if constexpr (U == 0) q.x = v;
    else if constexpr (U == 1) q.y = v;
    else if constexpr (U == 2) q.z = v;
    else q.w = v;
}

// ---------------------------------------------------------------------------
// Transpose: x[b][h][w] -> xq[b][col][pair] f2v, pair p = (row 2p, row 2p+1)
// ---------------------------------------------------------------------------
__global__ __launch_bounds__(512) void scnn_tr(const float* __restrict__ x,
                                               f2v* __restrict__ xq) {
    __shared__ float tile[HH][33];
    const int b = blockIdx.y;
    const int c0 = blockIdx.x * 32;
    const int t = threadIdx.x;
    const int col = t & 31;
    const int r0 = t >> 5;
    const float* xb = x + (size_t)b * HH * WW + c0;
#pragma unroll
    for (int k = 0; k < 24; ++k) {
        const int r = r0 + 16 * k;
        tile[r][col] = xb[(size_t)r * WW + col];
    }
    __syncthreads();
    f2v* xqb = xq + (size_t)b * BSTR + (size_t)c0 * NPAIR;
#pragma unroll
    for (int i = 0; i < 12; ++i) {
        const int idx = i * 512 + t;          // 0..6143 = cl*192 + pp
        const int cl = idx / NPAIR;
        const int pp = idx - cl * NPAIR;
        f2v v;
        v.x = tile[2 * pp][cl];
        v.y = tile[2 * pp + 1][cl];
        xqb[(size_t)cl * NPAIR + pp] = v;
    }
}

// 9-tap correlation + ReLU on one row-pair per lane (rows 2p, 2p+1).
// Window rows 2p-4..2p+5 = pairs p-2..p+2 via chained DPP. Even taps packed,
// odd taps scalar on pair halves.
static __device__ __forceinline__ f2v conv9(const f2v V, const f2v (&W)[KS]) {
    f2v A1, A0, A3, A4;
    A1.x = du(V.x);  A1.y = du(V.y);      // pair p-1 = (n2,n3)
    A0.x = du(A1.x); A0.y = du(A1.y);     // pair p-2 = (n0,n1)
    A3.x = dd(V.x);  A3.y = dd(V.y);      // pair p+1 = (n6,n7)
    A4.x = dd(A3.x); A4.y = dd(A3.y);     // pair p+2 = (n8,n9)
    f2v a = pk_mul(W[0], A0);
    a = pk_fma(W[2], A1, a);
    a = pk_fma(W[4], V,  a);
    a = pk_fma(W[6], A3, a);
    a = pk_fma(W[8], A4, a);
    float ax = a.x, ay = a.y;
    ax = fmaf(W[1].x, A0.y, ax);
    ax = fmaf(W[3].x, A1.y, ax);
    ax = fmaf(W[5].x, V.y,  ax);
    ax = fmaf(W[7].x, A3.y, ax);
    ay = fmaf(W[1].x, A1.x, ay);
    ay = fmaf(W[3].x, V.x,  ay);
    ay = fmaf(W[5].x, A3.x, ay);
    ay = fmaf(W[7].x, A4.x, ay);
    f2v r; r.x = fmaxf(ax, 0.f); r.y = fmaxf(ay, 0.f);
    return r;
}

// 4 waves/batch; wave w owns pairs 48w..48w+47 (lanes 8..55), computes 8 halo
// pairs each side redundantly; LDS state+halo-x refresh every 4 columns with a
// raw lgkmcnt+s_barrier (no vmcnt drain -> prefetch stays in flight).
__global__ __launch_bounds__(NT, 1) void scnn_scan(f2v* __restrict__ xq,
                                                   float* __restrict__ out,
                                                   const float* __restrict__ w_lr,
                                                   const float* __restrict__ w_rl) {
    __shared__ f2v lb[2][NPAIR];
    __shared__ f2v lx[2][NPAIR][4];

    const int b   = blockIdx.x;
    const int tid = threadIdx.x;
    const int wid = tid >> 6;
    const int l   = tid & 63;
    const int p   = 48 * wid - 8 + l;                 // this lane's pair (may be OOB)
    const bool inb   = (p >= 0) && (p < NPAIR);
    const bool owned = (l >= 8) && (l < 56);
    const int pc = p < 0 ? 0 : (p > NPAIR - 1 ? NPAIR - 1 : p);
    const int plo = 48 * wid, phi = 48 * wid + 47;
    const int po = p < plo ? plo : (p > phi ? phi : p);   // own-territory clamp

    f2v* xb = xq + (size_t)b * BSTR;
    float* outb = out + (size_t)b * HH * WW;

    f2v Wl[KS], Wr[KS];
#pragma unroll
    for (int k = 0; k < KS; ++k) {
        const float a = w_lr[k], c = w_rl[k];
        Wl[k].x = a; Wl[k].y = a;
        Wr[k].x = c; Wr[k].y = c;
    }

    int par = 0;
    f2v V;

#define MASKV(v) do { (v).x = inb ? (v).x : 0.f; (v).y = inb ? (v).y : 0.f; } while (0)

#define STEP1(XV, COL) do { \
    f2v _a = conv9(V, Wl); \
    V.x = (XV).x + _a.x; V.y = (XV).y + _a.y; \
    MASKV(V); \
    if (owned) xb[(size_t)(COL) * NPAIR + p] = V; \
} while (0)

#define REFRESH1(S) do { \
    if (owned) { \
        lb[par][p] = V; \
        lx[par][p][0] = Xr[(S) + 0]; lx[par][p][1] = Xr[(S) + 1]; \
        lx[par][p][2] = Xr[(S) + 2]; lx[par][p][3] = Xr[(S) + 3]; \
    } \
    asm volatile("s_waitcnt lgkmcnt(0)\n\ts_barrier" ::: "memory"); \
    { f2v _t = lb[par][pc]; \
      f2v _x0 = lx[par][pc][0], _x1 = lx[par][pc][1]; \
      f2v _x2 = lx[par][pc][2], _x3 = lx[par][pc][3]; \
      V.x = inb ? _t.x : 0.f; V.y = inb ? _t.y : 0.f; \
      if (!owned) { Xr[(S)+0] = _x0; Xr[(S)+1] = _x1; Xr[(S)+2] = _x2; Xr[(S)+3] = _x3; } \
    } \
    par ^= 1; \
} while (0)

#define REFRESH2() do { \
    if (owned) lb[par][p] = V; \
    asm volatile("s_waitcnt lgkmcnt(0)\n\ts_barrier" ::: "memory"); \
    { f2v _t = lb[par][pc]; V.x = inb ? _t.x : 0.f; V.y = inb ? _t.y : 0.f; } \
    par ^= 1; \
} while (0)

    // ======================= PASS 1 (left -> right) =======================
    {
        f2v Xr[8];
#pragma unroll
        for (int u = 0; u < 8; ++u) Xr[u] = xb[(size_t)(1 + u) * NPAIR + po];
        V = xb[po];                 // out1[0] = x[0]
        MASKV(V);
        REFRESH1(0);                // halo state + x(cols 1..4)
#pragma unroll 1
        for (int m = 0; m < 159; ++m) {
            const int q = 8 * m + 1;
            STEP1(Xr[0], q + 0); STEP1(Xr[1], q + 1);
            STEP1(Xr[2], q + 2); STEP1(Xr[3], q + 3);
            Xr[0] = xb[(size_t)(q + 8  > WW-1 ? WW-1 : q + 8 ) * NPAIR + po];
            Xr[1] = xb[(size_t)(q + 9  > WW-1 ? WW-1 : q + 9 ) * NPAIR + po];
            Xr[2] = xb[(size_t)(q + 10 > WW-1 ? WW-1 : q + 10) * NPAIR + po];
            Xr[3] = xb[(size_t)(q + 11 > WW-1 ? WW-1 : q + 11) * NPAIR + po];
            REFRESH1(4);
            STEP1(Xr[4], q + 4); STEP1(Xr[5], q + 5);
            STEP1(Xr[6], q + 6); STEP1(Xr[7], q + 7);
            Xr[4] = xb[(size_t)(q + 12 > WW-1 ? WW-1 : q + 12) * NPAIR + po];
            Xr[5] = xb[(size_t)(q + 13 > WW-1 ? WW-1 : q + 13) * NPAIR + po];
            Xr[6] = xb[(size_t)(q + 14 > WW-1 ? WW-1 : q + 14) * NPAIR + po];
            Xr[7] = xb[(size_t)(q + 15 > WW-1 ? WW-1 : q + 15) * NPAIR + po];
            REFRESH1(0);
        }
        // tail: cols 1273..1279
        STEP1(Xr[0], 1273); STEP1(Xr[1], 1274);
        STEP1(Xr[2], 1275); STEP1(Xr[3], 1276);
        REFRESH1(4);
        STEP1(Xr[4], 1277); STEP1(Xr[5], 1278); STEP1(Xr[6], 1279);
    }

    __syncthreads();   // one full barrier: drains pass-1 stores (vmcnt 0)

    // ======================= PASS 2 (right -> left) =======================
    {
        f2v Or[8];
#pragma unroll
        for (int u = 0; u < 8; ++u) Or[u] = xb[(size_t)(1278 - u) * NPAIR + pc];
        REFRESH2();                 // give halo lanes col-1279 state

        f4 obE[2], obO[2];

#define STEP2(C8, OV) do { \
    f2v _a = conv9(V, Wr); \
    V.x = (OV).x + _a.x; V.y = (OV).y + _a.y; \
    MASKV(V); \
    setc<(C8) & 3>(obE[(C8) >> 2], V.x); \
    setc<(C8) & 3>(obO[(C8) >> 2], V.y); \
} while (0)

#define FLUSH(W8) do { \
    if (owned) { \
        float* _r0 = outb + (size_t)(2 * p) * WW + (W8); \
        *(f4*)_r0 = obE[0]; *(f4*)(_r0 + 4) = obE[1]; \
        float* _r1 = _r0 + WW; \
        *(f4*)_r1 = obO[0]; *(f4*)(_r1 + 4) = obO[1]; \
    } \
} while (0)

        // emit col 1279 (= out1[1279], already in V)
        setc<3>(obE[1], V.x); setc<3>(obO[1], V.y);
#pragma unroll 1
        for (int m = 0; m < 159; ++m) {
            const int cA = 1278 - 8 * m;
            STEP2(6, Or[0]); STEP2(5, Or[1]);
            STEP2(4, Or[2]); STEP2(3, Or[3]);
            Or[0] = xb[(size_t)(cA - 8  < 0 ? 0 : cA - 8 ) * NPAIR + pc];
            Or[1] = xb[(size_t)(cA - 9  < 0 ? 0 : cA - 9 ) * NPAIR + pc];
            Or[2] = xb[(size_t)(cA - 10 < 0 ? 0 : cA - 10) * NPAIR + pc];
            Or[3] = xb[(size_t)(cA - 11 < 0 ? 0 : cA - 11) * NPAIR + pc];
            REFRESH2();
            STEP2(2, Or[4]); STEP2(1, Or[5]); STEP2(0, Or[6]);
            FLUSH(cA - 6);
            STEP2(7, Or[7]);
            Or[4] = xb[(size_t)(cA - 12 < 0 ? 0 : cA - 12) * NPAIR + pc];
            Or[5] = xb[(size_t)(cA - 13 < 0 ? 0 : cA - 13) * NPAIR + pc];
            Or[6] = xb[(size_t)(cA - 14 < 0 ? 0 : cA - 14) * NPAIR + pc];
            Or[7] = xb[(size_t)(cA - 15 < 0 ? 0 : cA - 15) * NPAIR + pc];
            REFRESH2();
        }
        // tail: cols 6..0
        STEP2(6, Or[0]); STEP2(5, Or[1]);
        STEP2(4, Or[2]); STEP2(3, Or[3]);
        REFRESH2();
        STEP2(2, Or[4]); STEP2(1, Or[5]); STEP2(0, Or[6]);
        FLUSH(0);
    }
}

extern "C" void kernel_launch(void* const* d_in, const int* in_sizes, int n_in,
                              void* d_out, int out_size, void* d_ws, size_t ws_size,
                              hipStream_t stream) {
    const float* x    = (const float*)d_in[0];
    const float* w_lr = (const float*)d_in[1];
    const float* w_rl = (const float*)d_in[2];
    float* out = (float*)d_out;
    f2v*   xq  = (f2v*)d_ws;    // 32 * 1280 * 192 f2v = 62.9 MB (in-place out1)

    scnn_tr<<<dim3(WW / 32, BB), 512, 0, stream>>>(x, xq);
    scnn_scan<<<BB, NT, 0, stream>>>(xq, out, w_lr, w_rl);
}

// Round 13
// 387.116 us; speedup vs baseline: 1.1027x; 1.1027x over previous
//
#include <hip/hip_runtime.h>

#define BB 32
#define HH 384
#define WW 1280
#define KS 9
#define NT 256                       // 4 waves per block
#define NPAIR 192                    // row-pairs per column
#define BSTR ((size_t)WW * NPAIR)    // f2v per batch

typedef float f2v __attribute__((ext_vector_type(2)));
typedef float4 f4;

static __device__ __forceinline__ f2v pk_mul(f2v a, f2v b) {
    f2v d; asm("v_pk_mul_f32 %0, %1, %2" : "=v"(d) : "v"(a), "v"(b)); return d;
}
static __device__ __forceinline__ f2v pk_fma(f2v a, f2v b, f2v c) {
    f2v d; asm("v_pk_fma_f32 %0, %1, %2, %3" : "=v"(d) : "v"(a), "v"(b), "v"(c)); return d;
}
// DPP wave shifts; bound_ctrl=true zero-fills edge lanes (verified rounds 2-12)
static __device__ __forceinline__ float du(float v) {   // lane i <- i-1; lane0 <- 0
    return __int_as_float(__builtin_amdgcn_mov_dpp(__float_as_int(v), 0x138, 0xf, 0xf, true));
}
static __device__ __forceinline__ float dd(float v) {   // lane i <- i+1; lane63 <- 0
    return __int_as_float(__builtin_amdgcn_mov_dpp(__float_as_int(v), 0x130, 0xf, 0xf, true));
}
template<int U> __device__ __forceinline__ void setc(f4& q, float v) {
    if constexpr (U == 0) q.x = v;
    else if constexpr (U == 1) q.y = v;
    else if constexpr (U == 2) q.z = v;
    else q.w = v;
}

// ---------------------------------------------------------------------------
// Transpose: x[b][h][w] -> xq[b][col][pair] f2v, pair p = (row 2p, row 2p+1)
// ---------------------------------------------------------------------------
__global__ __launch_bounds__(512) void scnn_tr(const float* __restrict__ x,
                                               f2v* __restrict__ xq) {
    __shared__ float tile[HH][33];
    const int b = blockIdx.y;
    const int c0 = blockIdx.x * 32;
    const int t = threadIdx.x;
    const int col = t & 31;
    const int r0 = t >> 5;
    const float* xb = x + (size_t)b * HH * WW + c0;
#pragma unroll
    for (int k = 0; k < 24; ++k) {
        const int r = r0 + 16 * k;
        tile[r][col] = xb[(size_t)r * WW + col];
    }
    __syncthreads();
    f2v* xqb = xq + (size_t)b * BSTR + (size_t)c0 * NPAIR;
#pragma unroll
    for (int i = 0; i < 12; ++i) {
        const int idx = i * 512 + t;          // 0..6143 = cl*192 + pp
        const int cl = idx / NPAIR;
        const int pp = idx - cl * NPAIR;
        f2v v;
        v.x = tile[2 * pp][cl];
        v.y = tile[2 * pp + 1][cl];
        xqb[(size_t)cl * NPAIR + pp] = v;
    }
}

// 9-tap correlation + ReLU on one row-pair per lane (rows 2p, 2p+1).
static __device__ __forceinline__ f2v conv9(const f2v V, const f2v (&W)[KS]) {
    f2v A1, A0, A3, A4;
    A1.x = du(V.x);  A1.y = du(V.y);      // pair p-1
    A0.x = du(A1.x); A0.y = du(A1.y);     // pair p-2
    A3.x = dd(V.x);  A3.y = dd(V.y);      // pair p+1
    A4.x = dd(A3.x); A4.y = dd(A3.y);     // pair p+2
    f2v a = pk_mul(W[0], A0);
    a = pk_fma(W[2], A1, a);
    a = pk_fma(W[4], V,  a);
    a = pk_fma(W[6], A3, a);
    a = pk_fma(W[8], A4, a);
    float ax = a.x, ay = a.y;
    ax = fmaf(W[1].x, A0.y, ax);
    ax = fmaf(W[3].x, A1.y, ax);
    ax = fmaf(W[5].x, V.y,  ax);
    ax = fmaf(W[7].x, A3.y, ax);
    ay = fmaf(W[1].x, A1.x, ay);
    ay = fmaf(W[3].x, V.x,  ay);
    ay = fmaf(W[5].x, A3.x, ay);
    ay = fmaf(W[7].x, A4.x, ay);
    f2v r; r.x = fmaxf(ax, 0.f); r.y = fmaxf(ay, 0.f);
    return r;
}

// 4 waves/batch; wave w owns pairs 48w..48w+47 (lanes 8..55), 8 redundant halo
// pairs each side; LDS state+halo-x refresh every 4 columns. All LDS arrays are
// FLOAT PLANES (lane stride 4B = 1 bank word) -> zero bank conflicts (round-12
// [p][4] f2v layout was a 16-way conflict: 491K conflict-cycles/dispatch).
__global__ __launch_bounds__(NT, 1) void scnn_scan(f2v* __restrict__ xq,
                                                   float* __restrict__ out,
                                                   const float* __restrict__ w_lr,
                                                   const float* __restrict__ w_rl) {
    __shared__ float lbx[2][NPAIR], lby[2][NPAIR];
    __shared__ float lxp[2][4][2][NPAIR];

    const int b   = blockIdx.x;
    const int tid = threadIdx.x;
    const int wid = tid >> 6;
    const int l   = tid & 63;
    const int p   = 48 * wid - 8 + l;                 // this lane's pair (may be OOB)
    const bool inb   = (p >= 0) && (p < NPAIR);
    const bool owned = (l >= 8) && (l < 56);
    const int pc = p < 0 ? 0 : (p > NPAIR - 1 ? NPAIR - 1 : p);
    const int plo = 48 * wid, phi = 48 * wid + 47;
    const int po = p < plo ? plo : (p > phi ? phi : p);   // own-territory clamp

    f2v* xb = xq + (size_t)b * BSTR;
    float* outb = out + (size_t)b * HH * WW;

    f2v Wl[KS], Wr[KS];
#pragma unroll
    for (int k = 0; k < KS; ++k) {
        const float a = w_lr[k], c = w_rl[k];
        Wl[k].x = a; Wl[k].y = a;
        Wr[k].x = c; Wr[k].y = c;
    }

    int par = 0;
    f2v V;

#define MASKV(v) do { (v).x = inb ? (v).x : 0.f; (v).y = inb ? (v).y : 0.f; } while (0)

#define STEP1(XV, COL) do { \
    f2v _a = conv9(V, Wl); \
    V.x = (XV).x + _a.x; V.y = (XV).y + _a.y; \
    MASKV(V); \
    if (owned) xb[(size_t)(COL) * NPAIR + p] = V; \
} while (0)

#define REFRESH1(S) do { \
    if (owned) { \
        lbx[par][p] = V.x; lby[par][p] = V.y; \
        lxp[par][0][0][p] = Xr[(S)+0].x; lxp[par][0][1][p] = Xr[(S)+0].y; \
        lxp[par][1][0][p] = Xr[(S)+1].x; lxp[par][1][1][p] = Xr[(S)+1].y; \
        lxp[par][2][0][p] = Xr[(S)+2].x; lxp[par][2][1][p] = Xr[(S)+2].y; \
        lxp[par][3][0][p] = Xr[(S)+3].x; lxp[par][3][1][p] = Xr[(S)+3].y; \
    } \
    asm volatile("s_waitcnt lgkmcnt(0)\n\ts_barrier" ::: "memory"); \
    { float _vx = lbx[par][pc], _vy = lby[par][pc]; \
      V.x = inb ? _vx : 0.f; V.y = inb ? _vy : 0.f; \
      if (!owned) { \
        Xr[(S)+0].x = lxp[par][0][0][pc]; Xr[(S)+0].y = lxp[par][0][1][pc]; \
        Xr[(S)+1].x = lxp[par][1][0][pc]; Xr[(S)+1].y = lxp[par][1][1][pc]; \
        Xr[(S)+2].x = lxp[par][2][0][pc]; Xr[(S)+2].y = lxp[par][2][1][pc]; \
        Xr[(S)+3].x = lxp[par][3][0][pc]; Xr[(S)+3].y = lxp[par][3][1][pc]; \
      } \
    } \
    par ^= 1; \
} while (0)

#define REFRESH2() do { \
    if (owned) { lbx[par][p] = V.x; lby[par][p] = V.y; } \
    asm volatile("s_waitcnt lgkmcnt(0)\n\ts_barrier" ::: "memory"); \
    { float _vx = lbx[par][pc], _vy = lby[par][pc]; \
      V.x = inb ? _vx : 0.f; V.y = inb ? _vy : 0.f; } \
    par ^= 1; \
} while (0)

    // ======================= PASS 1 (left -> right) =======================
    {
        f2v Xr[8];
#pragma unroll
        for (int u = 0; u < 8; ++u) Xr[u] = xb[(size_t)(1 + u) * NPAIR + po];
        V = xb[po];                 // out1[0] = x[0]
        MASKV(V);
        REFRESH1(0);                // halo state + x(cols 1..4)
#pragma unroll 1
        for (int m = 0; m < 159; ++m) {
            const int q = 8 * m + 1;
            STEP1(Xr[0], q + 0); STEP1(Xr[1], q + 1);
            STEP1(Xr[2], q + 2); STEP1(Xr[3], q + 3);
            Xr[0] = xb[(size_t)(q + 8  > WW-1 ? WW-1 : q + 8 ) * NPAIR + po];
            Xr[1] = xb[(size_t)(q + 9  > WW-1 ? WW-1 : q + 9 ) * NPAIR + po];
            Xr[2] = xb[(size_t)(q + 10 > WW-1 ? WW-1 : q + 10) * NPAIR + po];
            Xr[3] = xb[(size_t)(q + 11 > WW-1 ? WW-1 : q + 11) * NPAIR + po];
            REFRESH1(4);
            STEP1(Xr[4], q + 4); STEP1(Xr[5], q + 5);
            STEP1(Xr[6], q + 6); STEP1(Xr[7], q + 7);
            Xr[4] = xb[(size_t)(q + 12 > WW-1 ? WW-1 : q + 12) * NPAIR + po];
            Xr[5] = xb[(size_t)(q + 13 > WW-1 ? WW-1 : q + 13) * NPAIR + po];
            Xr[6] = xb[(size_t)(q + 14 > WW-1 ? WW-1 : q + 14) * NPAIR + po];
            Xr[7] = xb[(size_t)(q + 15 > WW-1 ? WW-1 : q + 15) * NPAIR + po];
            REFRESH1(0);
        }
        // tail: cols 1273..1279
        STEP1(Xr[0], 1273); STEP1(Xr[1], 1274);
        STEP1(Xr[2], 1275); STEP1(Xr[3], 1276);
        REFRESH1(4);
        STEP1(Xr[4], 1277); STEP1(Xr[5], 1278); STEP1(Xr[6], 1279);
    }

    __syncthreads();   // one full barrier: drains pass-1 stores (vmcnt 0)

    // ======================= PASS 2 (right -> left) =======================
    {
        f2v Or[8];
#pragma unroll
        for (int u = 0; u < 8; ++u) Or[u] = xb[(size_t)(1278 - u) * NPAIR + pc];
        REFRESH2();                 // give halo lanes col-1279 state

        f4 obE[2], obO[2];

#define STEP2(C8, OV) do { \
    f2v _a = conv9(V, Wr); \
    V.x = (OV).x + _a.x; V.y = (OV).y + _a.y; \
    MASKV(V); \
    setc<(C8) & 3>(obE[(C8) >> 2], V.x); \
    setc<(C8) & 3>(obO[(C8) >> 2], V.y); \
} while (0)

#define FLUSH(W8) do { \
    if (owned) { \
        float* _r0 = outb + (size_t)(2 * p) * WW + (W8); \
        *(f4*)_r0 = obE[0]; *(f4*)(_r0 + 4) = obE[1]; \
        float* _r1 = _r0 + WW; \
        *(f4*)_r1 = obO[0]; *(f4*)(_r1 + 4) = obO[1]; \
    } \
} while (0)

        // emit col 1279 (= out1[1279], already in V)
        setc<3>(obE[1], V.x); setc<3>(obO[1], V.y);
#pragma unroll 1
        for (int m = 0; m < 159; ++m) {
            const int cA = 1278 - 8 * m;
            STEP2(6, Or[0]); STEP2(5, Or[1]);
            STEP2(4, Or[2]); STEP2(3, Or[3]);
            Or[0] = xb[(size_t)(cA - 8  < 0 ? 0 : cA - 8 ) * NPAIR + pc];
            Or[1] = xb[(size_t)(cA - 9  < 0 ? 0 : cA - 9 ) * NPAIR + pc];
            Or[2] = xb[(size_t)(cA - 10 < 0 ? 0 : cA - 10) * NPAIR + pc];
            Or[3] = xb[(size_t)(cA - 11 < 0 ? 0 : cA - 11) * NPAIR + pc];
            REFRESH2();
            STEP2(2, Or[4]); STEP2(1, Or[5]); STEP2(0, Or[6]);
            FLUSH(cA - 6);
            STEP2(7, Or[7]);
            Or[4] = xb[(size_t)(cA - 12 < 0 ? 0 : cA - 12) * NPAIR + pc];
            Or[5] = xb[(size_t)(cA - 13 < 0 ? 0 : cA - 13) * NPAIR + pc];
            Or[6] = xb[(size_t)(cA - 14 < 0 ? 0 : cA - 14) * NPAIR + pc];
            Or[7] = xb[(size_t)(cA - 15 < 0 ? 0 : cA - 15) * NPAIR + pc];
            REFRESH2();
        }
        // tail: cols 6..0
        STEP2(6, Or[0]); STEP2(5, Or[1]);
        STEP2(4, Or[2]); STEP2(3, Or[3]);
        REFRESH2();
        STEP2(2, Or[4]); STEP2(1, Or[5]); STEP2(0, Or[6]);
        FLUSH(0);
    }
}

extern "C" void kernel_launch(void* const* d_in, const int* in_sizes, int n_in,
                              void* d_out, int out_size, void* d_ws, size_t ws_size,
                              hipStream_t stream) {
    const float* x    = (const float*)d_in[0];
    const float* w_lr = (const float*)d_in[1];
    const float* w_rl = (const float*)d_in[2];
    float* out = (float*)d_out;
    f2v*   xq  = (f2v*)d_ws;    // 32 * 1280 * 192 f2v = 62.9 MB (in-place out1)

    scnn_tr<<<dim3(WW / 32, BB), 512, 0, stream>>>(x, xq);
    scnn_scan<<<BB, NT, 0, stream>>>(xq, out, w_lr, w_rl);
}